// Round 11
// baseline (526.400 us; speedup 1.0000x reference)
//
#include <hip/hip_runtime.h>

#define NN 50000
#define NE 640000
#define BNEPS 1e-5f
#define SB 512
#define NBLK ((NN + SB - 1) / SB)  // 98

// workspace layout (float offsets) — total 13,665,280 floats = 54.7 MB
#define OFF_DINV 0
#define OFF_ST 51200
#define OFF_DEG 53248
#define OFF_ROWSTART 103424
#define OFF_CURSOR 153600
#define OFF_ESRC 203776
#define OFF_BSUM 843776
#define OFF_BOFF 843904
#define OFF_B0 844800
#define OFF_B1 7244800
#define OFF_WT0 13644800
#define OFF_WT1 13652992
#define OFF_WT2 13661184

typedef __attribute__((ext_vector_type(8))) __bf16 bf16x8;
typedef __attribute__((ext_vector_type(4))) float f32x4;

// ---- bf16 helpers ----
__device__ __forceinline__ float uplo(unsigned int u) {
  unsigned int v = u << 16;
  return __builtin_bit_cast(float, v);
}
__device__ __forceinline__ float uphi(unsigned int u) {
  unsigned int v = u & 0xffff0000u;
  return __builtin_bit_cast(float, v);
}
__device__ __forceinline__ unsigned int f2bf(float f) {
  unsigned int u = __builtin_bit_cast(unsigned int, f);
  return (u + 0x7fffu + ((u >> 16) & 1u)) >> 16;  // RNE
}

// ---------------- small kernels ----------------
__global__ __launch_bounds__(256) void init_k(int* __restrict__ deg,
                                              float* __restrict__ stats) {
  int i = blockIdx.x * 256 + threadIdx.x;
  if (i < NN) deg[i] = 0;
  if (i < 1024) stats[i] = 0.0f;
}

__global__ __launch_bounds__(256) void deg_k(const int* __restrict__ dst,
                                             int* __restrict__ deg) {
  int e = blockIdx.x * 256 + threadIdx.x;
  if (e < NE) atomicAdd(&deg[dst[e]], 1);
}

// ---- device-wide scan over deg ----
__global__ __launch_bounds__(SB) void block_sum_k(const int* __restrict__ deg,
                                                  int* __restrict__ bsum) {
  __shared__ int sh[SB];
  const int t = threadIdx.x;
  const int i = blockIdx.x * SB + t;
  sh[t] = (i < NN) ? deg[i] : 0;
  __syncthreads();
  for (int off = SB / 2; off > 0; off >>= 1) {
    if (t < off) sh[t] += sh[t + off];
    __syncthreads();
  }
  if (t == 0) bsum[blockIdx.x] = sh[0];
}

__global__ __launch_bounds__(128) void bscan_k(const int* __restrict__ bsum,
                                               int* __restrict__ boff) {
  __shared__ int sh[128];
  const int t = threadIdx.x;
  const int v = (t < NBLK) ? bsum[t] : 0;
  sh[t] = v;
  __syncthreads();
  for (int off = 1; off < 128; off <<= 1) {
    int u = (t >= off) ? sh[t - off] : 0;
    __syncthreads();
    sh[t] += u;
    __syncthreads();
  }
  if (t < NBLK) boff[t] = sh[t] - v;
}

__global__ __launch_bounds__(SB) void scan_fin_k(const int* __restrict__ deg,
                                                 const int* __restrict__ boff,
                                                 int* __restrict__ rowstart,
                                                 int* __restrict__ cursor,
                                                 float* __restrict__ dinv) {
  __shared__ int sh[SB];
  const int t = threadIdx.x;
  const int i = blockIdx.x * SB + t;
  const int v = (i < NN) ? deg[i] : 0;
  sh[t] = v;
  __syncthreads();
  for (int off = 1; off < SB; off <<= 1) {
    int u = (t >= off) ? sh[t - off] : 0;
    __syncthreads();
    sh[t] += u;
    __syncthreads();
  }
  if (i < NN) {
    const int excl = boff[blockIdx.x] + sh[t] - v;
    rowstart[i] = excl;
    cursor[i] = excl;
    dinv[i] = rsqrtf((float)v + 1.0f);
  }
  if (i == 0) rowstart[NN] = NE;
}

__global__ __launch_bounds__(256) void fill_k(const int* __restrict__ src,
                                              const int* __restrict__ dst,
                                              int* __restrict__ cursor,
                                              int* __restrict__ esrc) {
  int e = blockIdx.x * 256 + threadIdx.x;
  if (e < NE) {
    int p = atomicAdd(&cursor[dst[e]], 1);
    esrc[p] = src[e];
  }
}

// ---- weight transpose: W[128][nc] f32 -> Wt[nc][128] bf16, 3 weights ----
__global__ __launch_bounds__(256) void wtrans3_k(
    const float* __restrict__ W0, const float* __restrict__ W1,
    const float* __restrict__ W2, unsigned short* __restrict__ T0,
    unsigned short* __restrict__ T1, unsigned short* __restrict__ T2) {
  int f = blockIdx.x * 256 + threadIdx.x;
  if (f < 16384) {
    int k = f >> 7, n = f & 127;
    T0[n * 128 + k] = (unsigned short)f2bf(W0[f]);
  } else if (f < 32768) {
    int g = f - 16384;
    int k = g >> 7, n = g & 127;
    T1[n * 128 + k] = (unsigned short)f2bf(W1[g]);
  } else if (f < 40960) {
    int g = f - 32768;
    int k = g >> 6, n = g & 63;
    T2[n * 128 + k] = (unsigned short)f2bf(W2[g]);
  }
}

// ---------------- BN stats on x (layer 0 only) ----------------
__global__ __launch_bounds__(256) void bn_stats_k(const float* __restrict__ A,
                                                  float* __restrict__ sums,
                                                  float* __restrict__ sqs) {
  constexpr int CG = 32;
  constexpr int RG = 8;
  const int tc = threadIdx.x % CG;
  const int tr = threadIdx.x / CG;
  float s0 = 0, s1 = 0, s2 = 0, s3 = 0, q0 = 0, q1 = 0, q2 = 0, q3 = 0;
  for (int r = blockIdx.x * RG + tr; r < NN; r += gridDim.x * RG) {
    float4 v = *(const float4*)&A[(size_t)r * 128 + tc * 4];
    s0 += v.x; s1 += v.y; s2 += v.z; s3 += v.w;
    q0 += v.x * v.x; q1 += v.y * v.y; q2 += v.z * v.z; q3 += v.w * v.w;
  }
  __shared__ float rs[RG][128];
  __shared__ float rq[RG][128];
  rs[tr][tc * 4] = s0; rs[tr][tc * 4 + 1] = s1;
  rs[tr][tc * 4 + 2] = s2; rs[tr][tc * 4 + 3] = s3;
  rq[tr][tc * 4] = q0; rq[tr][tc * 4 + 1] = q1;
  rq[tr][tc * 4 + 2] = q2; rq[tr][tc * 4 + 3] = q3;
  __syncthreads();
  if (tr == 0) {
    for (int j = 0; j < 4; ++j) {
      int c = tc * 4 + j;
      float ts = 0, tq = 0;
      for (int g = 0; g < RG; ++g) { ts += rs[g][c]; tq += rq[g][c]; }
      atomicAdd(&sums[c], ts);
      atomicAdd(&sqs[c], tq);
    }
  }
}

// ---------------- MFMA GEMM (in-block BN finalize) ----------------
// C[M][NC] = pre(A) @ W, K=128, bf16 matrix cores, f32 accum.
// PRE: 0 = af[k]*v+bf[k] (f32 in) ; 1 = passthrough (bf16 in) ;
//      2 = relu(af[k]*(dinv[row]*v+preb[k])+bf[k]) (f32 in)
// af/bf computed per-block from raw sums/sqs/gamma/beta (BN fold).
// EPI: 0 = relu(acc+bias[c]) -> bf16 ; 1 = acc*dinv[row] -> bf16
template <int NC, int PRE, int EPI>
__global__ __launch_bounds__(256) void mfma_gemm_k(
    const void* __restrict__ Ain, const unsigned short* __restrict__ Wt,
    const float* __restrict__ bias, const float* __restrict__ sums,
    const float* __restrict__ sqs, const float* __restrict__ gamma,
    const float* __restrict__ beta, const float* __restrict__ preb,
    const float* __restrict__ dinv, unsigned short* __restrict__ O1) {
  constexpr int TM = 64;
  constexpr int NTILES = NC / 16;
  constexpr int CSTR = NC + 4;
  constexpr int ABYTES = TM * 128 * 2;
  constexpr int CBYTES = TM * CSTR * 4;
  constexpr int SMEM =
      (PRE == 1) ? CBYTES : (ABYTES > CBYTES ? ABYTES : CBYTES);
  __shared__ __align__(16) char smem[SMEM];
  __shared__ float af_s[128];
  __shared__ float bf_s[128];

  const int tid = threadIdx.x;
  const int row0 = blockIdx.x * TM;

  if constexpr (PRE != 1) {
    if (tid < 128) {
      float m = sums[tid] * (1.0f / NN);
      float v = sqs[tid] * (1.0f / NN) - m * m;
      float a = gamma[tid] * rsqrtf(v + BNEPS);
      af_s[tid] = a;
      bf_s[tid] = beta[tid] - m * a;
    }
    __syncthreads();
    const float* A = (const float*)Ain;
    for (int f = tid; f < TM * 32; f += 256) {
      const int r = f >> 5;
      const int c4 = f & 31;
      const int rg = row0 + r;
      float4 v = make_float4(0.f, 0.f, 0.f, 0.f);
      if (rg < NN) {
        v = *(const float4*)&A[(size_t)rg * 128 + c4 * 4];
        const float4 a4 = *(const float4*)&af_s[c4 * 4];
        const float4 b4 = *(const float4*)&bf_s[c4 * 4];
        if (PRE == 0) {
          v.x = fmaf(a4.x, v.x, b4.x);
          v.y = fmaf(a4.y, v.y, b4.y);
          v.z = fmaf(a4.z, v.z, b4.z);
          v.w = fmaf(a4.w, v.w, b4.w);
        } else {
          const float di = dinv[rg];
          const float4 p4 = *(const float4*)&preb[c4 * 4];
          v.x = fmaxf(fmaf(a4.x, fmaf(di, v.x, p4.x), b4.x), 0.f);
          v.y = fmaxf(fmaf(a4.y, fmaf(di, v.y, p4.y), b4.y), 0.f);
          v.z = fmaxf(fmaf(a4.z, fmaf(di, v.z, p4.z), b4.z), 0.f);
          v.w = fmaxf(fmaf(a4.w, fmaf(di, v.w, p4.w), b4.w), 0.f);
        }
      }
      uint2 wv;
      wv.x = f2bf(v.x) | (f2bf(v.y) << 16);
      wv.y = f2bf(v.z) | (f2bf(v.w) << 16);
      const int ba = (r * 256 + c4 * 8) ^ ((r & 7) << 4);
      *(uint2*)(smem + ba) = wv;
    }
    __syncthreads();
  }

  // ---- MFMA main loop ----
  const int w = tid >> 6;
  const int l = tid & 63;
  const int lr = l & 15;
  const int lg = l >> 4;
  f32x4 acc[NTILES];
#pragma unroll
  for (int i = 0; i < NTILES; ++i) acc[i] = (f32x4){0.f, 0.f, 0.f, 0.f};
  const int arow = w * 16 + lr;
#pragma unroll
  for (int kt = 0; kt < 4; ++kt) {
    bf16x8 a;
    if constexpr (PRE == 1) {
      const unsigned short* Ab = (const unsigned short*)Ain;
      a = __builtin_bit_cast(
          bf16x8, *(const uint4*)&Ab[(size_t)(row0 + arow) * 128 + kt * 32 + lg * 8]);
    } else {
      const int ba = (arow * 256 + kt * 64 + lg * 16) ^ ((arow & 7) << 4);
      a = __builtin_bit_cast(bf16x8, *(const uint4*)(smem + ba));
    }
#pragma unroll
    for (int nt = 0; nt < NTILES; ++nt) {
      bf16x8 b = __builtin_bit_cast(
          bf16x8, *(const uint4*)&Wt[(size_t)(nt * 16 + lr) * 128 + kt * 32 + lg * 8]);
      acc[nt] = __builtin_amdgcn_mfma_f32_16x16x32_bf16(a, b, acc[nt], 0, 0, 0);
    }
  }
  __syncthreads();

  // ---- C repack via LDS (coalesced bf16 global stores) ----
  float* Cl = (float*)smem;
#pragma unroll
  for (int nt = 0; nt < NTILES; ++nt)
#pragma unroll
    for (int r = 0; r < 4; ++r)
      Cl[(w * 16 + lg * 4 + r) * CSTR + nt * 16 + lr] = acc[nt][r];
  __syncthreads();

  constexpr int CG = NC / 4;
  constexpr int RPT = TM * CG / 256;
  const int tc = tid % CG;
  const int tr = tid / CG;
  float4 b4 = make_float4(0.f, 0.f, 0.f, 0.f);
  if constexpr (EPI == 0) b4 = *(const float4*)&bias[tc * 4];
#pragma unroll
  for (int i = 0; i < RPT; ++i) {
    const int row = tr * RPT + i;
    const int rg = row0 + row;
    if (rg < NN) {
      float4 v = *(const float4*)&Cl[row * CSTR + tc * 4];
      if (EPI == 0) {
        v.x = fmaxf(v.x + b4.x, 0.f);
        v.y = fmaxf(v.y + b4.y, 0.f);
        v.z = fmaxf(v.z + b4.z, 0.f);
        v.w = fmaxf(v.w + b4.w, 0.f);
      } else {
        const float s = dinv[rg];
        v.x *= s; v.y *= s; v.z *= s; v.w *= s;
      }
      uint2 o;
      o.x = f2bf(v.x) | (f2bf(v.y) << 16);
      o.y = f2bf(v.z) | (f2bf(v.w) << 16);
      *(uint2*)&O1[(size_t)rg * NC + tc * 4] = o;
    }
  }
}

// ---------------- CSR gather + fused BN stats ----------------
// ACC[d] = Y[d] + sum_in Y[esrc]; stats on z = dinv[d]*ACC[d] + cb[c]
template <int NC>
__global__ __launch_bounds__(256) void gather_bf_k(
    const int* __restrict__ rowstart, const int* __restrict__ esrc,
    const unsigned short* __restrict__ Y, float* __restrict__ ACC,
    const float* __restrict__ dinv, const float* __restrict__ cb,
    float* __restrict__ sums, float* __restrict__ sqs) {
  constexpr int CG = NC / 8;
  constexpr int RG = 256 / CG;
  const int tc = threadIdx.x % CG;
  const int tr = threadIdx.x / CG;
  const int c = tc * 8;
  float cbv[8];
#pragma unroll
  for (int j = 0; j < 8; ++j) cbv[j] = cb[c + j];
  float sa[8], qa[8];
#pragma unroll
  for (int j = 0; j < 8; ++j) { sa[j] = 0.f; qa[j] = 0.f; }

  for (int n = blockIdx.x * RG + tr; n < NN; n += gridDim.x * RG) {
    float a[8];
    {
      const uint4 p = *(const uint4*)&Y[(size_t)n * NC + c];
      a[0] = uplo(p.x); a[1] = uphi(p.x);
      a[2] = uplo(p.y); a[3] = uphi(p.y);
      a[4] = uplo(p.z); a[5] = uphi(p.z);
      a[6] = uplo(p.w); a[7] = uphi(p.w);
    }
    const int beg = rowstart[n];
    const int end = rowstart[n + 1];
    int e = beg;
    for (; e + 2 <= end; e += 2) {
      const int s0 = esrc[e];
      const int s1 = esrc[e + 1];
      const uint4 q0 = *(const uint4*)&Y[(size_t)s0 * NC + c];
      const uint4 q1 = *(const uint4*)&Y[(size_t)s1 * NC + c];
      a[0] += uplo(q0.x); a[1] += uphi(q0.x);
      a[2] += uplo(q0.y); a[3] += uphi(q0.y);
      a[4] += uplo(q0.z); a[5] += uphi(q0.z);
      a[6] += uplo(q0.w); a[7] += uphi(q0.w);
      a[0] += uplo(q1.x); a[1] += uphi(q1.x);
      a[2] += uplo(q1.y); a[3] += uphi(q1.y);
      a[4] += uplo(q1.z); a[5] += uphi(q1.z);
      a[6] += uplo(q1.w); a[7] += uphi(q1.w);
    }
    if (e < end) {
      const int s0 = esrc[e];
      const uint4 q0 = *(const uint4*)&Y[(size_t)s0 * NC + c];
      a[0] += uplo(q0.x); a[1] += uphi(q0.x);
      a[2] += uplo(q0.y); a[3] += uphi(q0.y);
      a[4] += uplo(q0.z); a[5] += uphi(q0.z);
      a[6] += uplo(q0.w); a[7] += uphi(q0.w);
    }
    *(float4*)&ACC[(size_t)n * NC + c] = make_float4(a[0], a[1], a[2], a[3]);
    *(float4*)&ACC[(size_t)n * NC + c + 4] = make_float4(a[4], a[5], a[6], a[7]);
    const float di = dinv[n];
#pragma unroll
    for (int j = 0; j < 8; ++j) {
      const float z = fmaf(a[j], di, cbv[j]);
      sa[j] += z;
      qa[j] += z * z;
    }
  }

  __shared__ float rs[RG][NC];
  __shared__ float rq[RG][NC];
#pragma unroll
  for (int j = 0; j < 8; ++j) { rs[tr][c + j] = sa[j]; rq[tr][c + j] = qa[j]; }
  __syncthreads();
  if (tr == 0) {
#pragma unroll
    for (int j = 0; j < 8; ++j) {
      float ts = 0.f, tq = 0.f;
      for (int g = 0; g < RG; ++g) { ts += rs[g][c + j]; tq += rq[g][c + j]; }
      atomicAdd(&sums[c + j], ts);
      atomicAdd(&sqs[c + j], tq);
    }
  }
}

// ---------------- final BN apply (in-block finalize) ----------------
__global__ __launch_bounds__(256) void final_k(
    const float* __restrict__ ACC2, const float* __restrict__ dinv,
    const float* __restrict__ cb, const float* __restrict__ s2,
    const float* __restrict__ q2, const float* __restrict__ gamma,
    const float* __restrict__ beta, float* __restrict__ out) {
  __shared__ float af_s[64];
  __shared__ float bf_s[64];
  if (threadIdx.x < 64) {
    float m = s2[threadIdx.x] * (1.0f / NN);
    float v = q2[threadIdx.x] * (1.0f / NN) - m * m;
    float a = gamma[threadIdx.x] * rsqrtf(v + BNEPS);
    af_s[threadIdx.x] = a;
    bf_s[threadIdx.x] = beta[threadIdx.x] - m * a;
  }
  __syncthreads();
  const int u = blockIdx.x * 256 + threadIdx.x;
  if (u >= NN * 16) return;
  const int r = u >> 4;
  const int c = (u & 15) * 4;
  const float di = dinv[r];
  float4 v = *(const float4*)&ACC2[(size_t)r * 64 + c];
  const float4 c4 = *(const float4*)&cb[c];
  const float4 a4 = *(const float4*)&af_s[c];
  const float4 b4 = *(const float4*)&bf_s[c];
  float4 o;
  o.x = fmaf(a4.x, fmaf(v.x, di, c4.x), b4.x);
  o.y = fmaf(a4.y, fmaf(v.y, di, c4.y), b4.y);
  o.z = fmaf(a4.z, fmaf(v.z, di, c4.z), b4.z);
  o.w = fmaf(a4.w, fmaf(v.w, di, c4.w), b4.w);
  *(float4*)&out[(size_t)r * 64 + c] = o;
}

extern "C" void kernel_launch(void* const* d_in, const int* in_sizes, int n_in,
                              void* d_out, int out_size, void* d_ws,
                              size_t ws_size, hipStream_t stream) {
  const float* x = (const float*)d_in[0];
  const int* ei = (const int*)d_in[1];
  const int* src = ei;
  const int* dst = ei + NE;
  const float* bn_in_g = (const float*)d_in[2];
  const float* bn_in_b = (const float*)d_in[3];
  const float* bn1_g = (const float*)d_in[4];
  const float* bn1_b = (const float*)d_in[5];
  const float* bn2_g = (const float*)d_in[6];
  const float* bn2_b = (const float*)d_in[7];
  const float* proj_W = (const float*)d_in[8];
  const float* proj_b = (const float*)d_in[9];
  const float* conv1_W = (const float*)d_in[10];
  const float* conv1_b = (const float*)d_in[11];
  const float* conv2_W = (const float*)d_in[12];
  const float* conv2_b = (const float*)d_in[13];
  float* out = (float*)d_out;

  float* ws = (float*)d_ws;
  float* dinv = ws + OFF_DINV;
  float* st = ws + OFF_ST;
  float* s0 = st;              float* q0 = st + 128;
  float* s1 = st + 256;        float* q1 = st + 384;
  float* s2 = st + 512;        float* q2 = st + 576;
  int* deg = (int*)(ws + OFF_DEG);
  int* rowstart = (int*)(ws + OFF_ROWSTART);
  int* cursor = (int*)(ws + OFF_CURSOR);
  int* esrc = (int*)(ws + OFF_ESRC);
  int* bsum = (int*)(ws + OFF_BSUM);
  int* boff = (int*)(ws + OFF_BOFF);
  float* B0 = ws + OFF_B0;
  float* B1 = ws + OFF_B1;
  unsigned short* Wt0 = (unsigned short*)(ws + OFF_WT0);  // proj  [128][128]
  unsigned short* Wt1 = (unsigned short*)(ws + OFF_WT1);  // conv1 [128][128]
  unsigned short* Wt2 = (unsigned short*)(ws + OFF_WT2);  // conv2 [64][128]
  // sequential aliasing: each buffer generation fully written before read
  unsigned short* H1bf = (unsigned short*)B0;  // gemm1 out (bf16), conv1 in
  unsigned short* Ybf = (unsigned short*)B1;   // conv1 out (bf16), gather1 in
  float* ACC = B0;                             // gather1 out (H1 dead)
  unsigned short* Y2bf = (unsigned short*)B1;  // conv2 out (Y dead)
  float* ACC2 = B0;                            // gather2 out (ACC dead)

  const int nb_n = (NN + 255) / 256;
  wtrans3_k<<<160, 256, 0, stream>>>(proj_W, conv1_W, conv2_W, Wt0, Wt1, Wt2);
  init_k<<<nb_n, 256, 0, stream>>>(deg, st);
  deg_k<<<(NE + 255) / 256, 256, 0, stream>>>(dst, deg);
  block_sum_k<<<NBLK, SB, 0, stream>>>(deg, bsum);
  bscan_k<<<1, 128, 0, stream>>>(bsum, boff);
  scan_fin_k<<<NBLK, SB, 0, stream>>>(deg, boff, rowstart, cursor, dinv);
  fill_k<<<(NE + 255) / 256, 256, 0, stream>>>(src, dst, cursor, esrc);

  // layer 0: stats on x; BN fold inside GEMM1
  bn_stats_k<<<256, 256, 0, stream>>>(x, s0, q0);

  const int nt64 = (NN + 63) / 64;  // 782 row tiles
  // H1bf = bf16(relu(BN(x) @ proj_W + proj_b))
  mfma_gemm_k<128, 0, 0><<<nt64, 256, 0, stream>>>(
      x, Wt0, proj_b, s0, q0, bn_in_g, bn_in_b, nullptr, dinv, H1bf);
  // conv1: Ybf = bf16((H1 @ conv1_W) * dinv[row])
  mfma_gemm_k<128, 1, 1><<<nt64, 256, 0, stream>>>(
      H1bf, Wt1, nullptr, nullptr, nullptr, nullptr, nullptr, nullptr, dinv,
      Ybf);
  // gather1 + BN1 stats on z1 = dinv*ACC + conv1_b
  gather_bf_k<128><<<1024, 256, 0, stream>>>(rowstart, esrc, Ybf, ACC, dinv,
                                             conv1_b, s1, q1);
  // conv2: input = relu(BN1(z1)) in staging (af1/bf1 from s1/q1); bf16 out
  mfma_gemm_k<64, 2, 1><<<nt64, 256, 0, stream>>>(
      ACC, Wt2, nullptr, s1, q1, bn1_g, bn1_b, conv1_b, dinv, Y2bf);
  // gather2 + BN2 stats on z2 = dinv*ACC2 + conv2_b
  gather_bf_k<64><<<512, 256, 0, stream>>>(rowstart, esrc, Y2bf, ACC2, dinv,
                                           conv2_b, s2, q2);
  final_k<<<(NN * 16 + 255) / 256, 256, 0, stream>>>(ACC2, dinv, conv2_b, s2,
                                                     q2, bn2_g, bn2_b, out);
}

// Round 12
// 282.426 us; speedup vs baseline: 1.8639x; 1.8639x over previous
//
#include <hip/hip_runtime.h>

#define NN 50000
#define NE 640000
#define BNEPS 1e-5f
#define SB 512
#define NBLK ((NN + SB - 1) / SB)  // 98

// workspace layout (float offsets) — total 13,665,280 floats = 54.7 MB
#define OFF_DINV 0
#define OFF_ST 51200
#define OFF_DEG 53248
#define OFF_ROWSTART 103424
#define OFF_CURSOR 153600
#define OFF_ESRC 203776
#define OFF_BSUM 843776
#define OFF_BOFF 843904
#define OFF_B0 844800
#define OFF_B1 7244800
#define OFF_WT0 13644800
#define OFF_WT1 13652992
#define OFF_WT2 13661184

typedef __attribute__((ext_vector_type(8))) __bf16 bf16x8;
typedef __attribute__((ext_vector_type(4))) float f32x4;

// ---- bf16 helpers ----
__device__ __forceinline__ float uplo(unsigned int u) {
  unsigned int v = u << 16;
  return __builtin_bit_cast(float, v);
}
__device__ __forceinline__ float uphi(unsigned int u) {
  unsigned int v = u & 0xffff0000u;
  return __builtin_bit_cast(float, v);
}
__device__ __forceinline__ unsigned int f2bf(float f) {
  unsigned int u = __builtin_bit_cast(unsigned int, f);
  return (u + 0x7fffu + ((u >> 16) & 1u)) >> 16;  // RNE
}

// ---------------- small kernels ----------------
__global__ __launch_bounds__(256) void init_k(int* __restrict__ deg,
                                              float* __restrict__ stats) {
  int i = blockIdx.x * 256 + threadIdx.x;
  if (i < NN) deg[i] = 0;
  if (i < 1024) stats[i] = 0.0f;
}

__global__ __launch_bounds__(256) void deg_k(const int* __restrict__ dst,
                                             int* __restrict__ deg) {
  int e = blockIdx.x * 256 + threadIdx.x;
  if (e < NE) atomicAdd(&deg[dst[e]], 1);
}

// ---- device-wide scan over deg ----
__global__ __launch_bounds__(SB) void block_sum_k(const int* __restrict__ deg,
                                                  int* __restrict__ bsum) {
  __shared__ int sh[SB];
  const int t = threadIdx.x;
  const int i = blockIdx.x * SB + t;
  sh[t] = (i < NN) ? deg[i] : 0;
  __syncthreads();
  for (int off = SB / 2; off > 0; off >>= 1) {
    if (t < off) sh[t] += sh[t + off];
    __syncthreads();
  }
  if (t == 0) bsum[blockIdx.x] = sh[0];
}

__global__ __launch_bounds__(128) void bscan_k(const int* __restrict__ bsum,
                                               int* __restrict__ boff) {
  __shared__ int sh[128];
  const int t = threadIdx.x;
  const int v = (t < NBLK) ? bsum[t] : 0;
  sh[t] = v;
  __syncthreads();
  for (int off = 1; off < 128; off <<= 1) {
    int u = (t >= off) ? sh[t - off] : 0;
    __syncthreads();
    sh[t] += u;
    __syncthreads();
  }
  if (t < NBLK) boff[t] = sh[t] - v;
}

__global__ __launch_bounds__(SB) void scan_fin_k(const int* __restrict__ deg,
                                                 const int* __restrict__ boff,
                                                 int* __restrict__ rowstart,
                                                 int* __restrict__ cursor,
                                                 float* __restrict__ dinv) {
  __shared__ int sh[SB];
  const int t = threadIdx.x;
  const int i = blockIdx.x * SB + t;
  const int v = (i < NN) ? deg[i] : 0;
  sh[t] = v;
  __syncthreads();
  for (int off = 1; off < SB; off <<= 1) {
    int u = (t >= off) ? sh[t - off] : 0;
    __syncthreads();
    sh[t] += u;
    __syncthreads();
  }
  if (i < NN) {
    const int excl = boff[blockIdx.x] + sh[t] - v;
    rowstart[i] = excl;
    cursor[i] = excl;
    dinv[i] = rsqrtf((float)v + 1.0f);
  }
  if (i == 0) rowstart[NN] = NE;
}

__global__ __launch_bounds__(256) void fill_k(const int* __restrict__ src,
                                              const int* __restrict__ dst,
                                              int* __restrict__ cursor,
                                              int* __restrict__ esrc) {
  int e = blockIdx.x * 256 + threadIdx.x;
  if (e < NE) {
    int p = atomicAdd(&cursor[dst[e]], 1);
    esrc[p] = src[e];
  }
}

// ---- weight transpose: W[128][nc] f32 -> Wt[nc][128] bf16, 3 weights ----
__global__ __launch_bounds__(256) void wtrans3_k(
    const float* __restrict__ W0, const float* __restrict__ W1,
    const float* __restrict__ W2, unsigned short* __restrict__ T0,
    unsigned short* __restrict__ T1, unsigned short* __restrict__ T2) {
  int f = blockIdx.x * 256 + threadIdx.x;
  if (f < 16384) {
    int k = f >> 7, n = f & 127;
    T0[n * 128 + k] = (unsigned short)f2bf(W0[f]);
  } else if (f < 32768) {
    int g = f - 16384;
    int k = g >> 7, n = g & 127;
    T1[n * 128 + k] = (unsigned short)f2bf(W1[g]);
  } else if (f < 40960) {
    int g = f - 32768;
    int k = g >> 6, n = g & 63;
    T2[n * 128 + k] = (unsigned short)f2bf(W2[g]);
  }
}

// ---------------- BN stats ----------------
// MODE 0: v = A[r][c] (f32 in)   MODE 1: v = A[r][c]*dinv[r] + cb[c]
template <int NC, int MODE>
__global__ __launch_bounds__(256) void bn_stats_k(const float* __restrict__ A,
                                                  const float* __restrict__ dinv,
                                                  const float* __restrict__ cb,
                                                  float* __restrict__ sums,
                                                  float* __restrict__ sqs) {
  constexpr int CG = NC / 4;
  constexpr int RG = 256 / CG;
  const int tc = threadIdx.x % CG;
  const int tr = threadIdx.x / CG;
  float cb0 = 0, cb1 = 0, cb2 = 0, cb3 = 0;
  if (MODE == 1) {
    cb0 = cb[tc * 4];
    cb1 = cb[tc * 4 + 1];
    cb2 = cb[tc * 4 + 2];
    cb3 = cb[tc * 4 + 3];
  }
  float s0 = 0, s1 = 0, s2 = 0, s3 = 0, q0 = 0, q1 = 0, q2 = 0, q3 = 0;
  for (int r = blockIdx.x * RG + tr; r < NN; r += gridDim.x * RG) {
    float4 v = *(const float4*)&A[(size_t)r * NC + tc * 4];
    if (MODE == 1) {
      float di = dinv[r];
      v.x = fmaf(v.x, di, cb0);
      v.y = fmaf(v.y, di, cb1);
      v.z = fmaf(v.z, di, cb2);
      v.w = fmaf(v.w, di, cb3);
    }
    s0 += v.x; s1 += v.y; s2 += v.z; s3 += v.w;
    q0 += v.x * v.x; q1 += v.y * v.y; q2 += v.z * v.z; q3 += v.w * v.w;
  }
  __shared__ float rs[RG][NC];
  __shared__ float rq[RG][NC];
  rs[tr][tc * 4] = s0; rs[tr][tc * 4 + 1] = s1;
  rs[tr][tc * 4 + 2] = s2; rs[tr][tc * 4 + 3] = s3;
  rq[tr][tc * 4] = q0; rq[tr][tc * 4 + 1] = q1;
  rq[tr][tc * 4 + 2] = q2; rq[tr][tc * 4 + 3] = q3;
  __syncthreads();
  if (tr == 0) {
    for (int j = 0; j < 4; ++j) {
      int c = tc * 4 + j;
      float ts = 0, tq = 0;
      for (int g = 0; g < RG; ++g) { ts += rs[g][c]; tq += rq[g][c]; }
      atomicAdd(&sums[c], ts);
      atomicAdd(&sqs[c], tq);
    }
  }
}

// ---------------- MFMA GEMM (in-block BN finalize) ----------------
// C[M][NC] = pre(A) @ W, K=128, bf16 matrix cores, f32 accum.
// PRE: 0 = af[k]*v+bf[k] (f32 in) ; 1 = passthrough (bf16 in) ;
//      2 = relu(af[k]*(dinv[row]*v+preb[k])+bf[k]) (f32 in)
// af/bf computed per-block from raw sums/sqs/gamma/beta (BN fold).
// EPI: 0 = relu(acc+bias[c]) -> bf16 ; 1 = acc*dinv[row] -> bf16
template <int NC, int PRE, int EPI>
__global__ __launch_bounds__(256) void mfma_gemm_k(
    const void* __restrict__ Ain, const unsigned short* __restrict__ Wt,
    const float* __restrict__ bias, const float* __restrict__ sums,
    const float* __restrict__ sqs, const float* __restrict__ gamma,
    const float* __restrict__ beta, const float* __restrict__ preb,
    const float* __restrict__ dinv, unsigned short* __restrict__ O1) {
  constexpr int TM = 64;
  constexpr int NTILES = NC / 16;
  constexpr int CSTR = NC + 4;
  constexpr int ABYTES = TM * 128 * 2;
  constexpr int CBYTES = TM * CSTR * 4;
  constexpr int SMEM =
      (PRE == 1) ? CBYTES : (ABYTES > CBYTES ? ABYTES : CBYTES);
  __shared__ __align__(16) char smem[SMEM];
  __shared__ float af_s[128];
  __shared__ float bf_s[128];

  const int tid = threadIdx.x;
  const int row0 = blockIdx.x * TM;

  if constexpr (PRE != 1) {
    if (tid < 128) {
      float m = sums[tid] * (1.0f / NN);
      float v = sqs[tid] * (1.0f / NN) - m * m;
      float a = gamma[tid] * rsqrtf(v + BNEPS);
      af_s[tid] = a;
      bf_s[tid] = beta[tid] - m * a;
    }
    __syncthreads();
    const float* A = (const float*)Ain;
    for (int f = tid; f < TM * 32; f += 256) {
      const int r = f >> 5;
      const int c4 = f & 31;
      const int rg = row0 + r;
      float4 v = make_float4(0.f, 0.f, 0.f, 0.f);
      if (rg < NN) {
        v = *(const float4*)&A[(size_t)rg * 128 + c4 * 4];
        const float4 a4 = *(const float4*)&af_s[c4 * 4];
        const float4 b4 = *(const float4*)&bf_s[c4 * 4];
        if (PRE == 0) {
          v.x = fmaf(a4.x, v.x, b4.x);
          v.y = fmaf(a4.y, v.y, b4.y);
          v.z = fmaf(a4.z, v.z, b4.z);
          v.w = fmaf(a4.w, v.w, b4.w);
        } else {
          const float di = dinv[rg];
          const float4 p4 = *(const float4*)&preb[c4 * 4];
          v.x = fmaxf(fmaf(a4.x, fmaf(di, v.x, p4.x), b4.x), 0.f);
          v.y = fmaxf(fmaf(a4.y, fmaf(di, v.y, p4.y), b4.y), 0.f);
          v.z = fmaxf(fmaf(a4.z, fmaf(di, v.z, p4.z), b4.z), 0.f);
          v.w = fmaxf(fmaf(a4.w, fmaf(di, v.w, p4.w), b4.w), 0.f);
        }
      }
      uint2 wv;
      wv.x = f2bf(v.x) | (f2bf(v.y) << 16);
      wv.y = f2bf(v.z) | (f2bf(v.w) << 16);
      const int ba = (r * 256 + c4 * 8) ^ ((r & 7) << 4);
      *(uint2*)(smem + ba) = wv;
    }
    __syncthreads();
  }

  // ---- MFMA main loop ----
  const int w = tid >> 6;
  const int l = tid & 63;
  const int lr = l & 15;
  const int lg = l >> 4;
  f32x4 acc[NTILES];
#pragma unroll
  for (int i = 0; i < NTILES; ++i) acc[i] = (f32x4){0.f, 0.f, 0.f, 0.f};
  const int arow = w * 16 + lr;
#pragma unroll
  for (int kt = 0; kt < 4; ++kt) {
    bf16x8 a;
    if constexpr (PRE == 1) {
      const unsigned short* Ab = (const unsigned short*)Ain;
      a = __builtin_bit_cast(
          bf16x8, *(const uint4*)&Ab[(size_t)(row0 + arow) * 128 + kt * 32 + lg * 8]);
    } else {
      const int ba = (arow * 256 + kt * 64 + lg * 16) ^ ((arow & 7) << 4);
      a = __builtin_bit_cast(bf16x8, *(const uint4*)(smem + ba));
    }
#pragma unroll
    for (int nt = 0; nt < NTILES; ++nt) {
      bf16x8 b = __builtin_bit_cast(
          bf16x8, *(const uint4*)&Wt[(size_t)(nt * 16 + lr) * 128 + kt * 32 + lg * 8]);
      acc[nt] = __builtin_amdgcn_mfma_f32_16x16x32_bf16(a, b, acc[nt], 0, 0, 0);
    }
  }
  __syncthreads();

  // ---- C repack via LDS (coalesced bf16 global stores) ----
  float* Cl = (float*)smem;
#pragma unroll
  for (int nt = 0; nt < NTILES; ++nt)
#pragma unroll
    for (int r = 0; r < 4; ++r)
      Cl[(w * 16 + lg * 4 + r) * CSTR + nt * 16 + lr] = acc[nt][r];
  __syncthreads();

  constexpr int CG = NC / 4;
  constexpr int RPT = TM * CG / 256;
  const int tc = tid % CG;
  const int tr = tid / CG;
  float4 b4 = make_float4(0.f, 0.f, 0.f, 0.f);
  if constexpr (EPI == 0) b4 = *(const float4*)&bias[tc * 4];
#pragma unroll
  for (int i = 0; i < RPT; ++i) {
    const int row = tr * RPT + i;
    const int rg = row0 + row;
    if (rg < NN) {
      float4 v = *(const float4*)&Cl[row * CSTR + tc * 4];
      if (EPI == 0) {
        v.x = fmaxf(v.x + b4.x, 0.f);
        v.y = fmaxf(v.y + b4.y, 0.f);
        v.z = fmaxf(v.z + b4.z, 0.f);
        v.w = fmaxf(v.w + b4.w, 0.f);
      } else {
        const float s = dinv[rg];
        v.x *= s; v.y *= s; v.z *= s; v.w *= s;
      }
      uint2 o;
      o.x = f2bf(v.x) | (f2bf(v.y) << 16);
      o.y = f2bf(v.z) | (f2bf(v.w) << 16);
      *(uint2*)&O1[(size_t)rg * NC + tc * 4] = o;
    }
  }
}

// ---------------- CSR gather aggregation (bf16 messages, f32 accum) ----
// ACC[d] = Y[d] (self loop) + sum_{e in in(d)} Y[esrc[e]]
template <int NC>
__global__ __launch_bounds__(256) void gather_bf_k(
    const int* __restrict__ rowstart, const int* __restrict__ esrc,
    const unsigned short* __restrict__ Y, float* __restrict__ ACC) {
  constexpr int CG = NC / 8;
  constexpr int RG = 256 / CG;
  const int tc = threadIdx.x % CG;
  const int tr = threadIdx.x / CG;
  const int n = blockIdx.x * RG + tr;
  if (n >= NN) return;
  const int c = tc * 8;
  float a[8];
  {
    const uint4 p = *(const uint4*)&Y[(size_t)n * NC + c];
    a[0] = uplo(p.x); a[1] = uphi(p.x);
    a[2] = uplo(p.y); a[3] = uphi(p.y);
    a[4] = uplo(p.z); a[5] = uphi(p.z);
    a[6] = uplo(p.w); a[7] = uphi(p.w);
  }
  const int beg = rowstart[n];
  const int end = rowstart[n + 1];
  int e = beg;
  for (; e + 2 <= end; e += 2) {
    const int s0 = esrc[e];
    const int s1 = esrc[e + 1];
    const uint4 q0 = *(const uint4*)&Y[(size_t)s0 * NC + c];
    const uint4 q1 = *(const uint4*)&Y[(size_t)s1 * NC + c];
    a[0] += uplo(q0.x); a[1] += uphi(q0.x);
    a[2] += uplo(q0.y); a[3] += uphi(q0.y);
    a[4] += uplo(q0.z); a[5] += uphi(q0.z);
    a[6] += uplo(q0.w); a[7] += uphi(q0.w);
    a[0] += uplo(q1.x); a[1] += uphi(q1.x);
    a[2] += uplo(q1.y); a[3] += uphi(q1.y);
    a[4] += uplo(q1.z); a[5] += uphi(q1.z);
    a[6] += uplo(q1.w); a[7] += uphi(q1.w);
  }
  if (e < end) {
    const int s0 = esrc[e];
    const uint4 q0 = *(const uint4*)&Y[(size_t)s0 * NC + c];
    a[0] += uplo(q0.x); a[1] += uphi(q0.x);
    a[2] += uplo(q0.y); a[3] += uphi(q0.y);
    a[4] += uplo(q0.z); a[5] += uphi(q0.z);
    a[6] += uplo(q0.w); a[7] += uphi(q0.w);
  }
  *(float4*)&ACC[(size_t)n * NC + c] = make_float4(a[0], a[1], a[2], a[3]);
  *(float4*)&ACC[(size_t)n * NC + c + 4] = make_float4(a[4], a[5], a[6], a[7]);
}

// ---------------- final BN apply (in-block finalize) ----------------
__global__ __launch_bounds__(256) void final_k(
    const float* __restrict__ ACC2, const float* __restrict__ dinv,
    const float* __restrict__ cb, const float* __restrict__ s2,
    const float* __restrict__ q2, const float* __restrict__ gamma,
    const float* __restrict__ beta, float* __restrict__ out) {
  __shared__ float af_s[64];
  __shared__ float bf_s[64];
  if (threadIdx.x < 64) {
    float m = s2[threadIdx.x] * (1.0f / NN);
    float v = q2[threadIdx.x] * (1.0f / NN) - m * m;
    float a = gamma[threadIdx.x] * rsqrtf(v + BNEPS);
    af_s[threadIdx.x] = a;
    bf_s[threadIdx.x] = beta[threadIdx.x] - m * a;
  }
  __syncthreads();
  const int u = blockIdx.x * 256 + threadIdx.x;
  if (u >= NN * 16) return;
  const int r = u >> 4;
  const int c = (u & 15) * 4;
  const float di = dinv[r];
  float4 v = *(const float4*)&ACC2[(size_t)r * 64 + c];
  const float4 c4 = *(const float4*)&cb[c];
  const float4 a4 = *(const float4*)&af_s[c];
  const float4 b4 = *(const float4*)&bf_s[c];
  float4 o;
  o.x = fmaf(a4.x, fmaf(v.x, di, c4.x), b4.x);
  o.y = fmaf(a4.y, fmaf(v.y, di, c4.y), b4.y);
  o.z = fmaf(a4.z, fmaf(v.z, di, c4.z), b4.z);
  o.w = fmaf(a4.w, fmaf(v.w, di, c4.w), b4.w);
  *(float4*)&out[(size_t)r * 64 + c] = o;
}

extern "C" void kernel_launch(void* const* d_in, const int* in_sizes, int n_in,
                              void* d_out, int out_size, void* d_ws,
                              size_t ws_size, hipStream_t stream) {
  const float* x = (const float*)d_in[0];
  const int* ei = (const int*)d_in[1];
  const int* src = ei;
  const int* dst = ei + NE;
  const float* bn_in_g = (const float*)d_in[2];
  const float* bn_in_b = (const float*)d_in[3];
  const float* bn1_g = (const float*)d_in[4];
  const float* bn1_b = (const float*)d_in[5];
  const float* bn2_g = (const float*)d_in[6];
  const float* bn2_b = (const float*)d_in[7];
  const float* proj_W = (const float*)d_in[8];
  const float* proj_b = (const float*)d_in[9];
  const float* conv1_W = (const float*)d_in[10];
  const float* conv1_b = (const float*)d_in[11];
  const float* conv2_W = (const float*)d_in[12];
  const float* conv2_b = (const float*)d_in[13];
  float* out = (float*)d_out;

  float* ws = (float*)d_ws;
  float* dinv = ws + OFF_DINV;
  float* st = ws + OFF_ST;
  float* s0 = st;              float* q0 = st + 128;
  float* s1 = st + 256;        float* q1 = st + 384;
  float* s2 = st + 512;        float* q2 = st + 576;
  int* deg = (int*)(ws + OFF_DEG);
  int* rowstart = (int*)(ws + OFF_ROWSTART);
  int* cursor = (int*)(ws + OFF_CURSOR);
  int* esrc = (int*)(ws + OFF_ESRC);
  int* bsum = (int*)(ws + OFF_BSUM);
  int* boff = (int*)(ws + OFF_BOFF);
  float* B0 = ws + OFF_B0;
  float* B1 = ws + OFF_B1;
  unsigned short* Wt0 = (unsigned short*)(ws + OFF_WT0);  // proj  [128][128]
  unsigned short* Wt1 = (unsigned short*)(ws + OFF_WT1);  // conv1 [128][128]
  unsigned short* Wt2 = (unsigned short*)(ws + OFF_WT2);  // conv2 [64][128]
  // sequential aliasing: each buffer generation fully written before read
  unsigned short* H1bf = (unsigned short*)B0;  // gemm1 out (bf16), conv1 in
  unsigned short* Ybf = (unsigned short*)B1;   // conv1 out (bf16), gather1 in
  float* ACC = B0;                             // gather1 out (H1 dead)
  unsigned short* Y2bf = (unsigned short*)B1;  // conv2 out (Y dead)
  float* ACC2 = B0;                            // gather2 out (ACC dead)

  const int nb_n = (NN + 255) / 256;
  wtrans3_k<<<160, 256, 0, stream>>>(proj_W, conv1_W, conv2_W, Wt0, Wt1, Wt2);
  init_k<<<nb_n, 256, 0, stream>>>(deg, st);
  deg_k<<<(NE + 255) / 256, 256, 0, stream>>>(dst, deg);
  block_sum_k<<<NBLK, SB, 0, stream>>>(deg, bsum);
  bscan_k<<<1, 128, 0, stream>>>(bsum, boff);
  scan_fin_k<<<NBLK, SB, 0, stream>>>(deg, boff, rowstart, cursor, dinv);
  fill_k<<<(NE + 255) / 256, 256, 0, stream>>>(src, dst, cursor, esrc);

  // layer 0: stats on x; BN fold inside GEMM1
  bn_stats_k<128, 0><<<256, 256, 0, stream>>>(x, nullptr, nullptr, s0, q0);

  const int nt64 = (NN + 63) / 64;  // 782 row tiles
  // H1bf = bf16(relu(BN(x) @ proj_W + proj_b))
  mfma_gemm_k<128, 0, 0><<<nt64, 256, 0, stream>>>(
      x, Wt0, proj_b, s0, q0, bn_in_g, bn_in_b, nullptr, dinv, H1bf);
  // conv1: Ybf = bf16((H1 @ conv1_W) * dinv[row])
  mfma_gemm_k<128, 1, 1><<<nt64, 256, 0, stream>>>(
      H1bf, Wt1, nullptr, nullptr, nullptr, nullptr, nullptr, nullptr, dinv,
      Ybf);
  gather_bf_k<128><<<(NN + 15) / 16, 256, 0, stream>>>(rowstart, esrc, Ybf,
                                                       ACC);
  // BN1 stats on z1 = dinv[r]*ACC + conv1_b
  bn_stats_k<128, 1><<<256, 256, 0, stream>>>(ACC, dinv, conv1_b, s1, q1);
  // conv2: input = relu(BN1(z1)) in staging (af1/bf1 from s1/q1); bf16 out
  mfma_gemm_k<64, 2, 1><<<nt64, 256, 0, stream>>>(
      ACC, Wt2, nullptr, s1, q1, bn1_g, bn1_b, conv1_b, dinv, Y2bf);
  gather_bf_k<64><<<(NN + 31) / 32, 256, 0, stream>>>(rowstart, esrc, Y2bf,
                                                      ACC2);
  // BN2 stats on z2 = dinv[r]*ACC2 + conv2_b
  bn_stats_k<64, 1><<<256, 256, 0, stream>>>(ACC2, dinv, conv2_b, s2, q2);
  final_k<<<(NN * 16 + 255) / 256, 256, 0, stream>>>(ACC2, dinv, conv2_b, s2,
                                                     q2, bn2_g, bn2_b, out);
}

// Round 13
// 264.575 us; speedup vs baseline: 1.9896x; 1.0675x over previous
//
#include <hip/hip_runtime.h>

#define NN 50000
#define NE 640000
#define BNEPS 1e-5f
#define NBLK 98  // ceil(NN/512)

// workspace layout (float offsets) — total 13,665,280 floats = 54.7 MB
#define OFF_DINV 0
#define OFF_ST 51200
#define OFF_DEG 53248
#define OFF_ROWSTART 103424
#define OFF_CURSOR 153600
#define OFF_ESRC 203776
#define OFF_BSUM 843776
#define OFF_BOFF 843904
#define OFF_B0 844800
#define OFF_B1 7244800
#define OFF_WT0 13644800
#define OFF_WT1 13652992
#define OFF_WT2 13661184

typedef __attribute__((ext_vector_type(8))) __bf16 bf16x8;
typedef __attribute__((ext_vector_type(4))) float f32x4;

// ---- bf16 helpers ----
__device__ __forceinline__ float uplo(unsigned int u) {
  unsigned int v = u << 16;
  return __builtin_bit_cast(float, v);
}
__device__ __forceinline__ float uphi(unsigned int u) {
  unsigned int v = u & 0xffff0000u;
  return __builtin_bit_cast(float, v);
}
__device__ __forceinline__ unsigned int f2bf(float f) {
  unsigned int u = __builtin_bit_cast(unsigned int, f);
  return (u + 0x7fffu + ((u >> 16) & 1u)) >> 16;  // RNE
}

// ================= K0: weight transpose + zero deg + zero stats ============
__global__ __launch_bounds__(256) void prep_k(
    const float* __restrict__ W0, const float* __restrict__ W1,
    const float* __restrict__ W2, unsigned short* __restrict__ T0,
    unsigned short* __restrict__ T1, unsigned short* __restrict__ T2,
    int* __restrict__ deg, float* __restrict__ stats) {
  const int bid = blockIdx.x;
  const int tid = threadIdx.x;
  if (bid < 160) {
    int f = bid * 256 + tid;
    if (f < 16384) {
      int k = f >> 7, n = f & 127;
      T0[n * 128 + k] = (unsigned short)f2bf(W0[f]);
    } else if (f < 32768) {
      int g = f - 16384;
      int k = g >> 7, n = g & 127;
      T1[n * 128 + k] = (unsigned short)f2bf(W1[g]);
    } else if (f < 40960) {
      int g = f - 32768;
      int k = g >> 6, n = g & 63;
      T2[n * 128 + k] = (unsigned short)f2bf(W2[g]);
    }
  } else if (bid < 356) {
    int i = (bid - 160) * 256 + tid;
    if (i < NN) deg[i] = 0;
  } else {
    int j = (bid - 356) * 256 + tid;
    if (j < 1024) stats[j] = 0.0f;
  }
}

// ---- BN-stats body (stride fixed at 256 blocks) ----
// MODE 0: v = A[r][c] f32      MODE 1: v = A[r][c]*dinv[r] + cb[c]
template <int NC, int MODE>
__device__ __forceinline__ void bn_stats_body(
    int sbid, int tid, const float* __restrict__ A,
    const float* __restrict__ dinv, const float* __restrict__ cb,
    float* __restrict__ sums, float* __restrict__ sqs,
    float (*rs)[NC], float (*rq)[NC]) {
  constexpr int CG = NC / 4;
  constexpr int RG = 256 / CG;
  const int tc = tid % CG;
  const int tr = tid / CG;
  float cb0 = 0, cb1 = 0, cb2 = 0, cb3 = 0;
  if (MODE == 1) {
    cb0 = cb[tc * 4];
    cb1 = cb[tc * 4 + 1];
    cb2 = cb[tc * 4 + 2];
    cb3 = cb[tc * 4 + 3];
  }
  float s0 = 0, s1 = 0, s2 = 0, s3 = 0, q0 = 0, q1 = 0, q2 = 0, q3 = 0;
  for (int r = sbid * RG + tr; r < NN; r += 256 * RG) {
    float4 v = *(const float4*)&A[(size_t)r * NC + tc * 4];
    if (MODE == 1) {
      float di = dinv[r];
      v.x = fmaf(v.x, di, cb0);
      v.y = fmaf(v.y, di, cb1);
      v.z = fmaf(v.z, di, cb2);
      v.w = fmaf(v.w, di, cb3);
    }
    s0 += v.x; s1 += v.y; s2 += v.z; s3 += v.w;
    q0 += v.x * v.x; q1 += v.y * v.y; q2 += v.z * v.z; q3 += v.w * v.w;
  }
  rs[tr][tc * 4] = s0; rs[tr][tc * 4 + 1] = s1;
  rs[tr][tc * 4 + 2] = s2; rs[tr][tc * 4 + 3] = s3;
  rq[tr][tc * 4] = q0; rq[tr][tc * 4 + 1] = q1;
  rq[tr][tc * 4 + 2] = q2; rq[tr][tc * 4 + 3] = q3;
  __syncthreads();
  if (tr == 0) {
    for (int j = 0; j < 4; ++j) {
      int c = tc * 4 + j;
      float ts = 0, tq = 0;
      for (int g = 0; g < RG; ++g) { ts += rs[g][c]; tq += rq[g][c]; }
      atomicAdd(&sums[c], ts);
      atomicAdd(&sqs[c], tq);
    }
  }
}

// ================= K1: bn_stats(x) [256 blocks] ∥ deg histogram ============
__global__ __launch_bounds__(256) void stats_deg_k(
    const float* __restrict__ x, float* __restrict__ s0,
    float* __restrict__ q0, const int* __restrict__ dst,
    int* __restrict__ deg) {
  __shared__ float rs[8][128];
  __shared__ float rq[8][128];
  const int bid = blockIdx.x;
  if (bid < 256) {
    bn_stats_body<128, 0>(bid, threadIdx.x, x, nullptr, nullptr, s0, q0, rs,
                          rq);
  } else {
    int e = (bid - 256) * 256 + threadIdx.x;
    if (e < NE) atomicAdd(&deg[dst[e]], 1);
  }
}

// ---------------- MFMA GEMM body (in-block BN finalize) ----------------
// C[M][NC] = pre(A) @ W, K=128, bf16 matrix cores, f32 accum.
// PRE: 0 = af[k]*v+bf[k] (f32 in) ; 1 = passthrough (bf16 in) ;
//      2 = relu(af[k]*(dinv[row]*v+preb[k])+bf[k]) (f32 in)
// EPI: 0 = relu(acc+bias[c]) -> bf16 ; 2 = plain -> bf16
template <int NC, int PRE, int EPI>
__device__ __forceinline__ void gemm_body(
    int bid, int tid, char* __restrict__ smem, float* __restrict__ af_s,
    float* __restrict__ bf_s, const void* __restrict__ Ain,
    const unsigned short* __restrict__ Wt, const float* __restrict__ bias,
    const float* __restrict__ sums, const float* __restrict__ sqs,
    const float* __restrict__ gamma, const float* __restrict__ beta,
    const float* __restrict__ preb, const float* __restrict__ dinv,
    unsigned short* __restrict__ O1) {
  constexpr int TM = 64;
  constexpr int NTILES = NC / 16;
  constexpr int CSTR = NC + 4;
  const int row0 = bid * TM;

  if constexpr (PRE != 1) {
    if (tid < 128) {
      float m = sums[tid] * (1.0f / NN);
      float v = sqs[tid] * (1.0f / NN) - m * m;
      float a = gamma[tid] * rsqrtf(v + BNEPS);
      af_s[tid] = a;
      bf_s[tid] = beta[tid] - m * a;
    }
    __syncthreads();
    const float* A = (const float*)Ain;
    for (int f = tid; f < TM * 32; f += 256) {
      const int r = f >> 5;
      const int c4 = f & 31;
      const int rg = row0 + r;
      float4 v = make_float4(0.f, 0.f, 0.f, 0.f);
      if (rg < NN) {
        v = *(const float4*)&A[(size_t)rg * 128 + c4 * 4];
        const float4 a4 = *(const float4*)&af_s[c4 * 4];
        const float4 b4 = *(const float4*)&bf_s[c4 * 4];
        if (PRE == 0) {
          v.x = fmaf(a4.x, v.x, b4.x);
          v.y = fmaf(a4.y, v.y, b4.y);
          v.z = fmaf(a4.z, v.z, b4.z);
          v.w = fmaf(a4.w, v.w, b4.w);
        } else {
          const float di = dinv[rg];
          const float4 p4 = *(const float4*)&preb[c4 * 4];
          v.x = fmaxf(fmaf(a4.x, fmaf(di, v.x, p4.x), b4.x), 0.f);
          v.y = fmaxf(fmaf(a4.y, fmaf(di, v.y, p4.y), b4.y), 0.f);
          v.z = fmaxf(fmaf(a4.z, fmaf(di, v.z, p4.z), b4.z), 0.f);
          v.w = fmaxf(fmaf(a4.w, fmaf(di, v.w, p4.w), b4.w), 0.f);
        }
      }
      uint2 wv;
      wv.x = f2bf(v.x) | (f2bf(v.y) << 16);
      wv.y = f2bf(v.z) | (f2bf(v.w) << 16);
      const int ba = (r * 256 + c4 * 8) ^ ((r & 7) << 4);
      *(uint2*)(smem + ba) = wv;
    }
    __syncthreads();
  }

  const int w = tid >> 6;
  const int l = tid & 63;
  const int lr = l & 15;
  const int lg = l >> 4;
  f32x4 acc[NTILES];
#pragma unroll
  for (int i = 0; i < NTILES; ++i) acc[i] = (f32x4){0.f, 0.f, 0.f, 0.f};
  const int arow = w * 16 + lr;
#pragma unroll
  for (int kt = 0; kt < 4; ++kt) {
    bf16x8 a;
    if constexpr (PRE == 1) {
      const unsigned short* Ab = (const unsigned short*)Ain;
      a = __builtin_bit_cast(
          bf16x8,
          *(const uint4*)&Ab[(size_t)(row0 + arow) * 128 + kt * 32 + lg * 8]);
    } else {
      const int ba = (arow * 256 + kt * 64 + lg * 16) ^ ((arow & 7) << 4);
      a = __builtin_bit_cast(bf16x8, *(const uint4*)(smem + ba));
    }
#pragma unroll
    for (int nt = 0; nt < NTILES; ++nt) {
      bf16x8 b = __builtin_bit_cast(
          bf16x8,
          *(const uint4*)&Wt[(size_t)(nt * 16 + lr) * 128 + kt * 32 + lg * 8]);
      acc[nt] = __builtin_amdgcn_mfma_f32_16x16x32_bf16(a, b, acc[nt], 0, 0, 0);
    }
  }
  __syncthreads();

  float* Cl = (float*)smem;
#pragma unroll
  for (int nt = 0; nt < NTILES; ++nt)
#pragma unroll
    for (int r = 0; r < 4; ++r)
      Cl[(w * 16 + lg * 4 + r) * CSTR + nt * 16 + lr] = acc[nt][r];
  __syncthreads();

  constexpr int CG = NC / 4;
  constexpr int RPT = TM * CG / 256;
  const int tc = tid % CG;
  const int tr = tid / CG;
  float4 b4 = make_float4(0.f, 0.f, 0.f, 0.f);
  if constexpr (EPI == 0) b4 = *(const float4*)&bias[tc * 4];
#pragma unroll
  for (int i = 0; i < RPT; ++i) {
    const int row = tr * RPT + i;
    const int rg = row0 + row;
    if (rg < NN) {
      float4 v = *(const float4*)&Cl[row * CSTR + tc * 4];
      if (EPI == 0) {
        v.x = fmaxf(v.x + b4.x, 0.f);
        v.y = fmaxf(v.y + b4.y, 0.f);
        v.z = fmaxf(v.z + b4.z, 0.f);
        v.w = fmaxf(v.w + b4.w, 0.f);
      }
      uint2 o;
      o.x = f2bf(v.x) | (f2bf(v.y) << 16);
      o.y = f2bf(v.z) | (f2bf(v.w) << 16);
      *(uint2*)&O1[(size_t)rg * NC + tc * 4] = o;
    }
  }
}

// ================= K2: GEMM1 [782] ∥ block_sum [98] ========================
__global__ __launch_bounds__(256) void gemm1_bsum_k(
    const float* __restrict__ x, const unsigned short* __restrict__ Wt0,
    const float* __restrict__ proj_b, const float* __restrict__ s0,
    const float* __restrict__ q0, const float* __restrict__ g0,
    const float* __restrict__ b0, unsigned short* __restrict__ H1bf,
    const int* __restrict__ deg, int* __restrict__ bsum) {
  __shared__ __align__(16) char smem[33792];
  __shared__ float af_s[128];
  __shared__ float bf_s[128];
  const int bid = blockIdx.x;
  const int tid = threadIdx.x;
  if (bid < 782) {
    gemm_body<128, 0, 0>(bid, tid, smem, af_s, bf_s, x, Wt0, proj_b, s0, q0,
                         g0, b0, nullptr, nullptr, H1bf);
  } else {
    int* sh = (int*)smem;
    const int cb = bid - 782;
    const int base = cb * 512;
    int v = 0;
    if (base + tid < NN) v += deg[base + tid];
    if (base + 256 + tid < NN) v += deg[base + 256 + tid];
    sh[tid] = v;
    __syncthreads();
    for (int off = 128; off > 0; off >>= 1) {
      if (tid < off) sh[tid] += sh[tid + off];
      __syncthreads();
    }
    if (tid == 0) bsum[cb] = sh[0];
  }
}

// ================= K3: conv1 GEMM [782] ∥ scan_fin [98] ====================
__global__ __launch_bounds__(256) void conv1_scan_k(
    const unsigned short* __restrict__ H1bf,
    const unsigned short* __restrict__ Wt1, unsigned short* __restrict__ Ybf,
    const int* __restrict__ deg, const int* __restrict__ bsum,
    int* __restrict__ rowstart, int* __restrict__ cursor,
    float* __restrict__ dinv) {
  __shared__ __align__(16) char smem[33792];
  __shared__ float af_s[128];
  __shared__ float bf_s[128];
  const int bid = blockIdx.x;
  const int tid = threadIdx.x;
  if (bid < 782) {
    gemm_body<128, 1, 2>(bid, tid, smem, af_s, bf_s, H1bf, Wt1, nullptr,
                         nullptr, nullptr, nullptr, nullptr, nullptr, nullptr,
                         Ybf);
  } else {
    int* sh = (int*)smem;          // 256 ints
    int* shb = ((int*)smem) + 256; // NBLK ints
    const int cb = bid - 782;
    if (tid < NBLK) shb[tid] = bsum[tid];
    __syncthreads();
    int goff = 0;
    for (int i = 0; i < cb; ++i) goff += shb[i];
    const int base = cb * 512;
    const int i0 = base + 2 * tid;
    const int i1 = i0 + 1;
    const int d0 = (i0 < NN) ? deg[i0] : 0;
    const int d1 = (i1 < NN) ? deg[i1] : 0;
    sh[tid] = d0 + d1;
    __syncthreads();
    for (int off = 1; off < 256; off <<= 1) {
      int u = (tid >= off) ? sh[tid - off] : 0;
      __syncthreads();
      sh[tid] += u;
      __syncthreads();
    }
    const int excl = goff + sh[tid] - (d0 + d1);
    if (i0 < NN) {
      rowstart[i0] = excl;
      cursor[i0] = excl;
      dinv[i0] = rsqrtf((float)d0 + 1.0f);
    }
    if (i1 < NN) {
      rowstart[i1] = excl + d0;
      cursor[i1] = excl + d0;
      dinv[i1] = rsqrtf((float)d1 + 1.0f);
    }
    if (cb == 0 && tid == 0) rowstart[NN] = NE;
  }
}

// ================= K4: CSR fill ============================================
__global__ __launch_bounds__(256) void fill_k(const int* __restrict__ src,
                                              const int* __restrict__ dst,
                                              int* __restrict__ cursor,
                                              int* __restrict__ esrc) {
  int e = blockIdx.x * 256 + threadIdx.x;
  if (e < NE) {
    int p = atomicAdd(&cursor[dst[e]], 1);
    esrc[p] = src[e];
  }
}

// ======= gather: ACC[d] = dinv[d]*Y[d] + sum_e dinv[src]*Y[src] (f32) ======
template <int NC>
__global__ __launch_bounds__(256) void gather_bf_k(
    const int* __restrict__ rowstart, const int* __restrict__ esrc,
    const unsigned short* __restrict__ Y, const float* __restrict__ dinv,
    float* __restrict__ ACC) {
  constexpr int CG = NC / 8;
  constexpr int RG = 256 / CG;
  const int tc = threadIdx.x % CG;
  const int tr = threadIdx.x / CG;
  const int n = blockIdx.x * RG + tr;
  if (n >= NN) return;
  const int c = tc * 8;
  float a[8];
  {
    const float dn = dinv[n];
    const uint4 p = *(const uint4*)&Y[(size_t)n * NC + c];
    a[0] = dn * uplo(p.x); a[1] = dn * uphi(p.x);
    a[2] = dn * uplo(p.y); a[3] = dn * uphi(p.y);
    a[4] = dn * uplo(p.z); a[5] = dn * uphi(p.z);
    a[6] = dn * uplo(p.w); a[7] = dn * uphi(p.w);
  }
  const int beg = rowstart[n];
  const int end = rowstart[n + 1];
  int e = beg;
  for (; e + 2 <= end; e += 2) {
    const int s0 = esrc[e];
    const int s1 = esrc[e + 1];
    const float d0 = dinv[s0];
    const float d1 = dinv[s1];
    const uint4 q0 = *(const uint4*)&Y[(size_t)s0 * NC + c];
    const uint4 q1 = *(const uint4*)&Y[(size_t)s1 * NC + c];
    a[0] = fmaf(d0, uplo(q0.x), a[0]); a[1] = fmaf(d0, uphi(q0.x), a[1]);
    a[2] = fmaf(d0, uplo(q0.y), a[2]); a[3] = fmaf(d0, uphi(q0.y), a[3]);
    a[4] = fmaf(d0, uplo(q0.z), a[4]); a[5] = fmaf(d0, uphi(q0.z), a[5]);
    a[6] = fmaf(d0, uplo(q0.w), a[6]); a[7] = fmaf(d0, uphi(q0.w), a[7]);
    a[0] = fmaf(d1, uplo(q1.x), a[0]); a[1] = fmaf(d1, uphi(q1.x), a[1]);
    a[2] = fmaf(d1, uplo(q1.y), a[2]); a[3] = fmaf(d1, uphi(q1.y), a[3]);
    a[4] = fmaf(d1, uplo(q1.z), a[4]); a[5] = fmaf(d1, uphi(q1.z), a[5]);
    a[6] = fmaf(d1, uplo(q1.w), a[6]); a[7] = fmaf(d1, uphi(q1.w), a[7]);
  }
  if (e < end) {
    const int s0 = esrc[e];
    const float d0 = dinv[s0];
    const uint4 q0 = *(const uint4*)&Y[(size_t)s0 * NC + c];
    a[0] = fmaf(d0, uplo(q0.x), a[0]); a[1] = fmaf(d0, uphi(q0.x), a[1]);
    a[2] = fmaf(d0, uplo(q0.y), a[2]); a[3] = fmaf(d0, uphi(q0.y), a[3]);
    a[4] = fmaf(d0, uplo(q0.z), a[4]); a[5] = fmaf(d0, uphi(q0.z), a[5]);
    a[6] = fmaf(d0, uplo(q0.w), a[6]); a[7] = fmaf(d0, uphi(q0.w), a[7]);
  }
  *(float4*)&ACC[(size_t)n * NC + c] = make_float4(a[0], a[1], a[2], a[3]);
  *(float4*)&ACC[(size_t)n * NC + c + 4] = make_float4(a[4], a[5], a[6], a[7]);
}

// ---------------- standalone BN stats (grid = 256) ----------------
template <int NC, int MODE>
__global__ __launch_bounds__(256) void bn_stats_k(const float* __restrict__ A,
                                                  const float* __restrict__ dinv,
                                                  const float* __restrict__ cb,
                                                  float* __restrict__ sums,
                                                  float* __restrict__ sqs) {
  __shared__ float rs[256 / (NC / 4)][NC];
  __shared__ float rq[256 / (NC / 4)][NC];
  bn_stats_body<NC, MODE>(blockIdx.x, threadIdx.x, A, dinv, cb, sums, sqs, rs,
                          rq);
}

// ---------------- standalone MFMA GEMM (conv2) ----------------
template <int NC, int PRE, int EPI>
__global__ __launch_bounds__(256) void mfma_gemm_k(
    const void* __restrict__ Ain, const unsigned short* __restrict__ Wt,
    const float* __restrict__ bias, const float* __restrict__ sums,
    const float* __restrict__ sqs, const float* __restrict__ gamma,
    const float* __restrict__ beta, const float* __restrict__ preb,
    const float* __restrict__ dinv, unsigned short* __restrict__ O1) {
  constexpr int CBYTES = 64 * (NC + 4) * 4;
  constexpr int SMEM = (CBYTES > 16384) ? CBYTES : 16384;
  __shared__ __align__(16) char smem[SMEM];
  __shared__ float af_s[128];
  __shared__ float bf_s[128];
  gemm_body<NC, PRE, EPI>(blockIdx.x, threadIdx.x, smem, af_s, bf_s, Ain, Wt,
                          bias, sums, sqs, gamma, beta, preb, dinv, O1);
}

// ---------------- final BN apply (in-block finalize) ----------------
__global__ __launch_bounds__(256) void final_k(
    const float* __restrict__ ACC2, const float* __restrict__ dinv,
    const float* __restrict__ cb, const float* __restrict__ s2,
    const float* __restrict__ q2, const float* __restrict__ gamma,
    const float* __restrict__ beta, float* __restrict__ out) {
  __shared__ float af_s[64];
  __shared__ float bf_s[64];
  if (threadIdx.x < 64) {
    float m = s2[threadIdx.x] * (1.0f / NN);
    float v = q2[threadIdx.x] * (1.0f / NN) - m * m;
    float a = gamma[threadIdx.x] * rsqrtf(v + BNEPS);
    af_s[threadIdx.x] = a;
    bf_s[threadIdx.x] = beta[threadIdx.x] - m * a;
  }
  __syncthreads();
  const int u = blockIdx.x * 256 + threadIdx.x;
  if (u >= NN * 16) return;
  const int r = u >> 4;
  const int c = (u & 15) * 4;
  const float di = dinv[r];
  float4 v = *(const float4*)&ACC2[(size_t)r * 64 + c];
  const float4 c4 = *(const float4*)&cb[c];
  const float4 a4 = *(const float4*)&af_s[c];
  const float4 b4 = *(const float4*)&bf_s[c];
  float4 o;
  o.x = fmaf(a4.x, fmaf(v.x, di, c4.x), b4.x);
  o.y = fmaf(a4.y, fmaf(v.y, di, c4.y), b4.y);
  o.z = fmaf(a4.z, fmaf(v.z, di, c4.z), b4.z);
  o.w = fmaf(a4.w, fmaf(v.w, di, c4.w), b4.w);
  *(float4*)&out[(size_t)r * 64 + c] = o;
}

extern "C" void kernel_launch(void* const* d_in, const int* in_sizes, int n_in,
                              void* d_out, int out_size, void* d_ws,
                              size_t ws_size, hipStream_t stream) {
  const float* x = (const float*)d_in[0];
  const int* ei = (const int*)d_in[1];
  const int* src = ei;
  const int* dst = ei + NE;
  const float* bn_in_g = (const float*)d_in[2];
  const float* bn_in_b = (const float*)d_in[3];
  const float* bn1_g = (const float*)d_in[4];
  const float* bn1_b = (const float*)d_in[5];
  const float* bn2_g = (const float*)d_in[6];
  const float* bn2_b = (const float*)d_in[7];
  const float* proj_W = (const float*)d_in[8];
  const float* proj_b = (const float*)d_in[9];
  const float* conv1_W = (const float*)d_in[10];
  const float* conv1_b = (const float*)d_in[11];
  const float* conv2_W = (const float*)d_in[12];
  const float* conv2_b = (const float*)d_in[13];
  float* out = (float*)d_out;

  float* ws = (float*)d_ws;
  float* dinv = ws + OFF_DINV;
  float* st = ws + OFF_ST;
  float* s0 = st;              float* q0 = st + 128;
  float* s1 = st + 256;        float* q1 = st + 384;
  float* s2 = st + 512;        float* q2 = st + 576;
  int* deg = (int*)(ws + OFF_DEG);
  int* rowstart = (int*)(ws + OFF_ROWSTART);
  int* cursor = (int*)(ws + OFF_CURSOR);
  int* esrc = (int*)(ws + OFF_ESRC);
  int* bsum = (int*)(ws + OFF_BSUM);
  float* B0 = ws + OFF_B0;
  float* B1 = ws + OFF_B1;
  unsigned short* Wt0 = (unsigned short*)(ws + OFF_WT0);  // proj  [128][128]
  unsigned short* Wt1 = (unsigned short*)(ws + OFF_WT1);  // conv1 [128][128]
  unsigned short* Wt2 = (unsigned short*)(ws + OFF_WT2);  // conv2 [64][128]
  // sequential aliasing: each buffer generation fully written before read
  unsigned short* H1bf = (unsigned short*)B0;  // K2 out, K3 in
  unsigned short* Ybf = (unsigned short*)B1;   // K3 out, gather1 in
  float* ACC = B0;                             // gather1 out (H1 dead)
  unsigned short* Y2bf = (unsigned short*)B1;  // conv2 out (Y dead)
  float* ACC2 = B0;                            // gather2 out (ACC dead)

  // K0: weight transpose + zero deg + zero stats
  prep_k<<<360, 256, 0, stream>>>(proj_W, conv1_W, conv2_W, Wt0, Wt1, Wt2, deg,
                                  st);
  // K1: bn_stats(x) [256] ∥ deg histogram [2500]
  stats_deg_k<<<2756, 256, 0, stream>>>(x, s0, q0, dst, deg);
  // K2: GEMM1 (BN(x)@W0, relu+bias) [782] ∥ block_sum [98]
  gemm1_bsum_k<<<880, 256, 0, stream>>>(x, Wt0, proj_b, s0, q0, bn_in_g,
                                        bn_in_b, H1bf, deg, bsum);
  // K3: conv1 GEMM (plain xw, bf16) [782] ∥ scan_fin (rowstart/cursor/dinv) [98]
  conv1_scan_k<<<880, 256, 0, stream>>>(H1bf, Wt1, Ybf, deg, bsum, rowstart,
                                        cursor, dinv);
  // K4: CSR fill
  fill_k<<<(NE + 255) / 256, 256, 0, stream>>>(src, dst, cursor, esrc);
  // K5: gather1 (dinv-weighted)
  gather_bf_k<128><<<(NN + 15) / 16, 256, 0, stream>>>(rowstart, esrc, Ybf,
                                                       dinv, ACC);
  // K6: BN1 stats on z1 = dinv*ACC + conv1_b
  bn_stats_k<128, 1><<<256, 256, 0, stream>>>(ACC, dinv, conv1_b, s1, q1);
  // K7: conv2 GEMM (PRE=2 relu(BN1), plain bf16 out)
  mfma_gemm_k<64, 2, 2><<<782, 256, 0, stream>>>(
      ACC, Wt2, nullptr, s1, q1, bn1_g, bn1_b, conv1_b, dinv, Y2bf);
  // K8: gather2 (dinv-weighted)
  gather_bf_k<64><<<(NN + 31) / 32, 256, 0, stream>>>(rowstart, esrc, Y2bf,
                                                      dinv, ACC2);
  // K9: BN2 stats on z2 = dinv*ACC2 + conv2_b
  bn_stats_k<64, 1><<<256, 256, 0, stream>>>(ACC2, dinv, conv2_b, s2, q2);
  // K10: final BN apply
  final_k<<<(NN * 16 + 255) / 256, 256, 0, stream>>>(ACC2, dinv, conv2_b, s2,
                                                     q2, bn2_g, bn2_b, out);
}